// Round 12
// baseline (89.383 us; speedup 1.0000x reference)
//
#include <hip/hip_runtime.h>
#include <hip/hip_bf16.h>

// Problem constants
#define TOK  4096      // tokens = 16*16*16
#define CH   384       // hidden
#define NH   6         // heads
#define HD   64        // head dim
#define NQKV 1152      // 3*CH

typedef __bf16 bf16x8 __attribute__((ext_vector_type(8)));
typedef float f32x4  __attribute__((ext_vector_type(4)));
typedef float f32x16 __attribute__((ext_vector_type(16)));
typedef unsigned short u16x8 __attribute__((ext_vector_type(8)));
typedef unsigned short u16x4 __attribute__((ext_vector_type(4)));
typedef unsigned int   u32x2 __attribute__((ext_vector_type(2)));
typedef unsigned int   u32x4 __attribute__((ext_vector_type(4)));

__device__ __forceinline__ unsigned short f2bf(float f) {
    unsigned int u = __builtin_bit_cast(unsigned int, f);
    u += 0x7FFFu + ((u >> 16) & 1u);   // round-to-nearest-even
    return (unsigned short)(u >> 16);
}

__device__ __forceinline__ float bf2f(unsigned short s) {
    return __builtin_bit_cast(float, (unsigned int)s << 16);
}

// pack two f32 -> one u32 of 2 bf16 (folds to v_cvt_pk_bf16_f32: 1 VALU op)
__device__ __forceinline__ unsigned int pk2(float a, float b) {
    __bf16 x = (__bf16)a, y = (__bf16)b;
    unsigned short ux = __builtin_bit_cast(unsigned short, x);
    unsigned short uy = __builtin_bit_cast(unsigned short, y);
    return (unsigned int)ux | ((unsigned int)uy << 16);
}

__device__ __forceinline__ f32x4 mfma_bf16(u16x8 a, u16x8 b, f32x4 c) {
    return __builtin_amdgcn_mfma_f32_16x16x32_bf16(
        __builtin_bit_cast(bf16x8, a), __builtin_bit_cast(bf16x8, b), c, 0, 0, 0);
}

__device__ __forceinline__ f32x16 mfma32(u16x8 a, u16x8 b, f32x16 c) {
    return __builtin_amdgcn_mfma_f32_32x32x16_bf16(
        __builtin_bit_cast(bf16x8, a), __builtin_bit_cast(bf16x8, b), c, 0, 0, 0);
}

// v_permlane32_swap_b32 (fallback: shfl)
__device__ __forceinline__ void plswap(unsigned int &x, unsigned int &y, int hi) {
#if __has_builtin(__builtin_amdgcn_permlane32_swap)
    u32x2 r = __builtin_amdgcn_permlane32_swap(x, y, false, false);
    x = r[0]; y = r[1];
#else
    unsigned int xs = (unsigned int)__shfl_xor((int)x, 32, 64);
    unsigned int ys = (unsigned int)__shfl_xor((int)y, 32, 64);
    unsigned int nx = hi ? ys : x;
    unsigned int ny = hi ? y  : xs;
    x = nx; y = ny;
#endif
}

__device__ __forceinline__ float partner32(float v, int hi) {
    unsigned int a = __builtin_bit_cast(unsigned int, v);
    unsigned int b = a;
    plswap(a, b, hi);
    return __builtin_bit_cast(float, hi ? a : b);
}

// ---------------------------------------------------------------------------
// Kernel 1: qkv = xt @ W_qkv.   A = xt[t][c] (x stored [c][t]), B = W_qkv[c][n]
// Q is scaled by 0.125*log2(e) (softmax scale + exp2-domain fold).
// Writes: Q [h][t][64], K [h][t][64], V^T [h][64][t]  (bf16)
// R5's 64x64 form (grid 64x18 = 1152 blocks): empirically best "others" time.
// 128x128 (288 blocks) regressed ~4 µs from tail quantization (1.1 block/CU).
// ---------------------------------------------------------------------------
__global__ __launch_bounds__(256) void qkv_kernel(
    const float* __restrict__ x, const float* __restrict__ w,
    unsigned short* __restrict__ qws, unsigned short* __restrict__ kws,
    unsigned short* __restrict__ vtws)
{
    __shared__ __align__(16) unsigned short As[64][32];   // [m][k]
    __shared__ __align__(16) unsigned short Bs[64][32];   // [n][k]
    const int tid = threadIdx.x;
    const int t0 = blockIdx.x * 64;
    const int by = blockIdx.y;            // 0..17
    const int n0 = by * 64;
    const int lane = tid & 63;
    const int wid  = tid >> 6;
    const int wr = wid >> 1, wc = wid & 1;
    const int l15 = lane & 15, lg = lane >> 4;
    const int sm  = tid & 63;
    const int skg = tid >> 6;

    f32x4 acc[2][2] = {};

    for (int k0 = 0; k0 < CH; k0 += 32) {
        float a[8], b[8];
        #pragma unroll
        for (int j = 0; j < 8; ++j) {
            a[j] = x[(k0 + skg*8 + j) * TOK + t0 + sm];
            b[j] = w[(k0 + skg*8 + j) * NQKV + n0 + sm];
        }
        u32x4 aw = { pk2(a[0],a[1]), pk2(a[2],a[3]), pk2(a[4],a[5]), pk2(a[6],a[7]) };
        u32x4 bw = { pk2(b[0],b[1]), pk2(b[2],b[3]), pk2(b[4],b[5]), pk2(b[6],b[7]) };
        __syncthreads();
        *reinterpret_cast<u32x4*>(&As[sm][skg*8]) = aw;
        *reinterpret_cast<u32x4*>(&Bs[sm][skg*8]) = bw;
        __syncthreads();

        u16x8 afr[2], bfr[2];
        #pragma unroll
        for (int mi = 0; mi < 2; ++mi)
            afr[mi] = *reinterpret_cast<const u16x8*>(&As[wr*32 + mi*16 + l15][lg*8]);
        #pragma unroll
        for (int ni = 0; ni < 2; ++ni)
            bfr[ni] = *reinterpret_cast<const u16x8*>(&Bs[wc*32 + ni*16 + l15][lg*8]);
        #pragma unroll
        for (int mi = 0; mi < 2; ++mi)
            #pragma unroll
            for (int ni = 0; ni < 2; ++ni)
                acc[mi][ni] = mfma_bf16(afr[mi], bfr[ni], acc[mi][ni]);
    }

    // qscale = 0.125 * log2(e): logits come out in exp2 domain
    const float qscale = (by < 6) ? 0.18033688011112042f : 1.0f;
    const int head = by % 6;
    #pragma unroll
    for (int mi = 0; mi < 2; ++mi)
    #pragma unroll
    for (int ni = 0; ni < 2; ++ni)
    #pragma unroll
    for (int r = 0; r < 4; ++r) {
        int t   = t0 + wr*32 + mi*16 + lg*4 + r;
        int dim = wc*32 + ni*16 + l15;
        unsigned short v = f2bf(acc[mi][ni][r] * qscale);
        if (by < 6)        qws[head*(TOK*HD) + t*HD + dim] = v;
        else if (by < 12)  kws[head*(TOK*HD) + t*HD + dim] = v;
        else               vtws[head*(TOK*HD) + dim*TOK + t] = v;
    }
}

// ---------------------------------------------------------------------------
// Kernel 2: flash attention — R11 EXACT (verified 41.7-42.2 µs, VGPR 76).
// 32x32 swapped-QK^T, in-register softmax, no max tracking (exp2-domain
// logits, |s| << 127). KBLK=128 staged per barrier pair; two sequential
// 64-key halves with st[2] reused. Register prefetch of next tile. lsum
// partner-merge deferred to epilogue. KS=4 now (half partial-O traffic).
// ---------------------------------------------------------------------------
__global__ __launch_bounds__(256, 3) void attn_kernel(
    const unsigned short* __restrict__ qws, const unsigned short* __restrict__ kws,
    const unsigned short* __restrict__ vtws, unsigned short* __restrict__ odst,
    float* __restrict__ lpart, int clen, int nchunks)
{
    __shared__ __align__(16) unsigned short Ks[128][64];    // [key][d], swizzled ^(row&7)
    __shared__ __align__(16) unsigned short Vts[64][128];   // [d][key], swizzled ^(row&15)
    const int tid = threadIdx.x;
    const int h  = blockIdx.y;
    const int chunk = blockIdx.z;
    const int kbeg = chunk * clen, kend = kbeg + clen;
    const int lane = tid & 63, wid = tid >> 6;
    const int l31 = lane & 31, hi = lane >> 5;
    const int krow = tid >> 3, kch = tid & 7;     // K staging: +i*32 rows
    const int vrow = tid >> 4, vch = tid & 15;    // V staging: +i*16 rows
    const int qrow = blockIdx.x * 128 + wid * 32 + l31;    // this lane's q row

    const unsigned short* qh = qws  + h*(TOK*HD);
    const unsigned short* kh = kws  + h*(TOK*HD);
    const unsigned short* vh = vtws + h*(TOK*HD);

    // Q B-frags (col=lane&31=q, k=d = c*16 + hi*8 + j)
    u16x8 qf[4];
    #pragma unroll
    for (int c = 0; c < 4; ++c)
        qf[c] = *reinterpret_cast<const u16x8*>(&qh[(size_t)qrow*HD + c*16 + hi*8]);

    f32x16 oaccT[2] = {};        // O^T: col=q(l31), row=d_local
    float lsum = 0.f;            // lane-local partial; partner-merged at end

    // prologue prefetch of tile 0 (4 K-frags + 4 V-frags per thread)
    u16x8 kreg[4], vreg[4];
    #pragma unroll
    for (int i = 0; i < 4; ++i) {
        kreg[i] = *reinterpret_cast<const u16x8*>(
            &kh[(size_t)(kbeg + krow + i*32)*HD + kch*8]);
        vreg[i] = *reinterpret_cast<const u16x8*>(
            &vh[(size_t)(vrow + i*16)*TOK + kbeg + vch*8]);
    }

    for (int kt = kbeg; kt < kend; kt += 128) {
        __syncthreads();   // prev tile's LDS reads done
        #pragma unroll
        for (int i = 0; i < 4; ++i) {
            int kr = krow + i*32;
            int vr = vrow + i*16;
            *reinterpret_cast<u16x8*>(&Ks[kr][(kch ^ (kr & 7))*8])   = kreg[i];
            *reinterpret_cast<u16x8*>(&Vts[vr][(vch ^ (vr & 15))*8]) = vreg[i];
        }
        const int ktn = (kt + 128 < kend) ? (kt + 128) : kt;
        #pragma unroll
        for (int i = 0; i < 4; ++i) {
            kreg[i] = *reinterpret_cast<const u16x8*>(
                &kh[(size_t)(ktn + krow + i*32)*HD + kch*8]);
            vreg[i] = *reinterpret_cast<const u16x8*>(
                &vh[(size_t)(vrow + i*16)*TOK + ktn + vch*8]);
        }
        __syncthreads();   // staging visible

        // two sequential 64-key halves (verified 64-key pipeline per half)
        #pragma unroll
        for (int H = 0; H < 2; ++H) {
            // S^T[key][q]: A=K rows (key = H*64 + g*32 + l31), B=Q
            f32x16 st[2] = {};
            #pragma unroll
            for (int g = 0; g < 2; ++g) {
                int r = H*64 + g*32 + l31;
                #pragma unroll
                for (int c = 0; c < 4; ++c) {
                    int chs = (c*2 + hi) ^ (r & 7);
                    u16x8 kf = *reinterpret_cast<const u16x8*>(&Ks[r][chs*8]);
                    st[g] = mfma32(kf, qf[c], st[g]);
                }
            }

            // p = exp2(s) directly (no max tracking)
            #pragma unroll
            for (int g = 0; g < 2; ++g)
                #pragma unroll
                for (int e = 0; e < 16; ++e)
                    st[g][e] = __builtin_amdgcn_exp2f(st[g][e]);

            // row sum: log-depth tree (lane-local; partner merge deferred)
            float tr[16];
            #pragma unroll
            for (int e = 0; e < 16; ++e)
                tr[e] = st[0][e] + st[1][e];
            #pragma unroll
            for (int w = 8; w >= 1; w >>= 1)
                #pragma unroll
                for (int e = 0; e < w; ++e)
                    tr[e] += tr[e+w];
            lsum += tr[0];

            // pack P to bf16 words: key(g, reg=4s+m) = H*64 + g*32 + 8s + m + 4*hi
            unsigned int wAw[2][4], wBw[2][4];
            #pragma unroll
            for (int g = 0; g < 2; ++g)
                #pragma unroll
                for (int s = 0; s < 4; ++s) {
                    wAw[g][s] = pk2(st[g][4*s+0], st[g][4*s+1]);
                    wBw[g][s] = pk2(st[g][4*s+2], st[g][4*s+3]);
                }

            // O^T += V^T P^T over this half's 64 key-columns
            #pragma unroll
            for (int ks = 0; ks < 4; ++ks) {
                int g = ks >> 1, u = (ks & 1) * 2;
                unsigned int a0 = wAw[g][u], a1 = wAw[g][u+1];
                unsigned int b0 = wBw[g][u], b1 = wBw[g][u+1];
                plswap(a0, a1, hi);
                plswap(b0, b1, hi);
                u32x4 af = { a0, b0, a1, b1 };
                u16x8 pfr = __builtin_bit_cast(u16x8, af);
                int cc = H*8 + ks*2 + hi;          // V col-chunk (16 per row)
                #pragma unroll
                for (int dh = 0; dh < 2; ++dh) {
                    int r = dh*32 + l31;
                    int ccs = cc ^ (r & 15);
                    u16x8 vf = *reinterpret_cast<const u16x8*>(&Vts[r][ccs*8]);
                    oaccT[dh] = mfma32(vf, pfr, oaccT[dh]);
                }
            }
        }
    }

    // merge lane partials (lane and lane^32 hold complementary key halves)
    lsum += partner32(lsum, hi);

    // epilogue: O^T element (dh, reg=4s+m) -> d = dh*32 + 8s + 4*hi + m, q = qrow
    if (nchunks == 1) {
        float inv = 1.0f / lsum;
        #pragma unroll
        for (int dh = 0; dh < 2; ++dh)
            #pragma unroll
            for (int s = 0; s < 4; ++s) {
                u16x4 v;
                #pragma unroll
                for (int m = 0; m < 4; ++m)
                    v[m] = f2bf(oaccT[dh][4*s+m] * inv);
                *reinterpret_cast<u16x4*>(
                    &odst[(size_t)qrow*CH + h*HD + dh*32 + s*8 + hi*4]) = v;
            }
    } else {
        const size_t cb = (size_t)(chunk*NH + h)*TOK;
        #pragma unroll
        for (int dh = 0; dh < 2; ++dh)
            #pragma unroll
            for (int s = 0; s < 4; ++s) {
                u16x4 v;
                #pragma unroll
                for (int m = 0; m < 4; ++m)
                    v[m] = f2bf(oaccT[dh][4*s+m]);
                *reinterpret_cast<u16x4*>(
                    &odst[(cb + qrow)*HD + dh*32 + s*8 + hi*4]) = v;
            }
        if (hi == 0)
            lpart[cb + qrow] = lsum;
    }
}

// ---------------------------------------------------------------------------
// Kernel 3a (KS>1): out = (combine(opart)/l) @ W_out + b_out — combine FUSED
// into the A-staging: per K-step each staging thread sums its nchunks
// opart fragments in fp32, scales by the per-(head,row) inverse (precomputed
// once — the thread's row is fixed), packs to bf16. Deletes the combine
// kernel, its launch gap, and the op intermediate round-trip. opart re-reads
// across the 6 n-tiles are L3-resident (12.6 MB << 256 MB).
// ---------------------------------------------------------------------------
__global__ __launch_bounds__(256) void out_fused_kernel(
    const unsigned short* __restrict__ opart, const float* __restrict__ lpart,
    const float* __restrict__ w, const float* __restrict__ bias,
    float* __restrict__ out, int nchunks)
{
    __shared__ __align__(16) unsigned short As[64][32];
    __shared__ __align__(16) unsigned short Bs[64][32];
    const int tid = threadIdx.x;
    const int t0 = blockIdx.x * 64;
    const int n0 = blockIdx.y * 64;
    const int lane = tid & 63, wid = tid >> 6;
    const int wr = wid >> 1, wc = wid & 1;
    const int l15 = lane & 15, lg = lane >> 4;
    const int sm = tid & 63, skg = tid >> 6;
    const int trow = t0 + sm;            // this thread's staging row (fixed)

    // per-head inverse normalizers for this row
    float inv[NH];
    #pragma unroll
    for (int h = 0; h < NH; ++h) {
        float wsum = 0.f;
        for (int c = 0; c < nchunks; ++c)
            wsum += lpart[(size_t)(c*NH + h)*TOK + trow];
        inv[h] = 1.0f / wsum;
    }

    f32x4 acc[2][2] = {};

    for (int k0 = 0; k0 < CH; k0 += 32) {
        const int kbase = k0 + skg*8;     // 8 contiguous k's, all in one head
        const int h = kbase >> 6, dim = kbase & 63;
        float o[8] = {};
        for (int c = 0; c < nchunks; ++c) {
            u16x8 ov = *reinterpret_cast<const u16x8*>(
                &opart[((size_t)(c*NH + h)*TOK + trow)*HD + dim]);
            #pragma unroll
            for (int j = 0; j < 8; ++j)
                o[j] += bf2f(ov[j]);
        }
        const float s = inv[h];
        u32x4 aw = { pk2(o[0]*s,o[1]*s), pk2(o[2]*s,o[3]*s),
                     pk2(o[4]*s,o[5]*s), pk2(o[6]*s,o[7]*s) };
        float b[8];
        #pragma unroll
        for (int j = 0; j < 8; ++j)
            b[j] = w[(k0 + skg*8 + j) * CH + n0 + sm];
        u32x4 bw = { pk2(b[0],b[1]), pk2(b[2],b[3]), pk2(b[4],b[5]), pk2(b[6],b[7]) };
        __syncthreads();
        *reinterpret_cast<u32x4*>(&As[sm][skg*8]) = aw;
        *reinterpret_cast<u32x4*>(&Bs[sm][skg*8]) = bw;
        __syncthreads();

        u16x8 afr[2], bfr[2];
        #pragma unroll
        for (int mi = 0; mi < 2; ++mi)
            afr[mi] = *reinterpret_cast<const u16x8*>(&As[wr*32 + mi*16 + l15][lg*8]);
        #pragma unroll
        for (int ni = 0; ni < 2; ++ni)
            bfr[ni] = *reinterpret_cast<const u16x8*>(&Bs[wc*32 + ni*16 + l15][lg*8]);
        #pragma unroll
        for (int mi = 0; mi < 2; ++mi)
            #pragma unroll
            for (int ni = 0; ni < 2; ++ni)
                acc[mi][ni] = mfma_bf16(afr[mi], bfr[ni], acc[mi][ni]);
    }

    #pragma unroll
    for (int mi = 0; mi < 2; ++mi)
    #pragma unroll
    for (int ni = 0; ni < 2; ++ni)
    #pragma unroll
    for (int r = 0; r < 4; ++r) {
        int t = t0 + wr*32 + mi*16 + lg*4 + r;
        int n = n0 + wc*32 + ni*16 + l15;
        out[t*CH + n] = acc[mi][ni][r] + bias[n];
    }
}

// ---------------------------------------------------------------------------
// Kernel 3b (KS==1 fallback): out = O @ W_out + b_out from normalized op.
// ---------------------------------------------------------------------------
__global__ __launch_bounds__(256) void out_kernel(
    const unsigned short* __restrict__ ob, const float* __restrict__ w,
    const float* __restrict__ bias, float* __restrict__ out)
{
    __shared__ __align__(16) unsigned short As[64][32];
    __shared__ __align__(16) unsigned short Bs[64][32];
    const int tid = threadIdx.x;
    const int t0 = blockIdx.x * 64;
    const int n0 = blockIdx.y * 64;
    const int lane = tid & 63, wid = tid >> 6;
    const int wr = wid >> 1, wc = wid & 1;
    const int l15 = lane & 15, lg = lane >> 4;
    const int sm = tid & 63, skg = tid >> 6;

    f32x4 acc[2][2] = {};

    for (int k0 = 0; k0 < CH; k0 += 32) {
        u16x8 av = *reinterpret_cast<const u16x8*>(&ob[(size_t)(t0+sm)*CH + k0 + skg*8]);
        float b[8];
        #pragma unroll
        for (int j = 0; j < 8; ++j)
            b[j] = w[(k0 + skg*8 + j) * CH + n0 + sm];
        u32x4 bw = { pk2(b[0],b[1]), pk2(b[2],b[3]), pk2(b[4],b[5]), pk2(b[6],b[7]) };
        __syncthreads();
        *reinterpret_cast<u16x8*>(&As[sm][skg*8]) = av;
        *reinterpret_cast<u32x4*>(&Bs[sm][skg*8]) = bw;
        __syncthreads();

        u16x8 afr[2], bfr[2];
        #pragma unroll
        for (int mi = 0; mi < 2; ++mi)
            afr[mi] = *reinterpret_cast<const u16x8*>(&As[wr*32 + mi*16 + l15][lg*8]);
        #pragma unroll
        for (int ni = 0; ni < 2; ++ni)
            bfr[ni] = *reinterpret_cast<const u16x8*>(&Bs[wc*32 + ni*16 + l15][lg*8]);
        #pragma unroll
        for (int mi = 0; mi < 2; ++mi)
            #pragma unroll
            for (int ni = 0; ni < 2; ++ni)
                acc[mi][ni] = mfma_bf16(afr[mi], bfr[ni], acc[mi][ni]);
    }

    #pragma unroll
    for (int mi = 0; mi < 2; ++mi)
    #pragma unroll
    for (int ni = 0; ni < 2; ++ni)
    #pragma unroll
    for (int r = 0; r < 4; ++r) {
        int t = t0 + wr*32 + mi*16 + lg*4 + r;
        int n = n0 + wc*32 + ni*16 + l15;
        out[t*CH + n] = acc[mi][ni][r] + bias[n];
    }
}

// ---------------------------------------------------------------------------
extern "C" void kernel_launch(void* const* d_in, const int* in_sizes, int n_in,
                              void* d_out, int out_size, void* d_ws, size_t ws_size,
                              hipStream_t stream) {
    const float* x    = (const float*)d_in[0];   // [384][4096] (c-major)
    const float* wqkv = (const float*)d_in[1];   // [384][1152]
    const float* wout = (const float*)d_in[2];   // [384][384]
    const float* bout = (const float*)d_in[3];   // [384]
    float* out = (float*)d_out;                  // [4096][384] flat

    unsigned short* ws  = (unsigned short*)d_ws;
    unsigned short* qp  = ws;
    unsigned short* kp  = qp + NH*TOK*HD;
    unsigned short* vtp = kp + NH*TOK*HD;
    unsigned short* op  = vtp + NH*TOK*HD;

    const size_t baseB = (size_t)(3*NH*TOK*HD + TOK*CH) * 2;
    const size_t perC  = (size_t)NH*TOK*HD*2 + (size_t)NH*TOK*4;   // opart + lpart
    int KS = 1;
    if      (baseB + 4*perC <= ws_size) KS = 4;
    else if (baseB + 2*perC <= ws_size) KS = 2;

    qkv_kernel<<<dim3(64, 18), 256, 0, stream>>>(x, wqkv, qp, kp, vtp);

    if (KS > 1) {
        unsigned short* opart = op + (size_t)TOK*CH;
        float* lp = (float*)(opart + (size_t)KS*NH*TOK*HD);
        attn_kernel<<<dim3(TOK/128, 6, KS), 256, 0, stream>>>(
            qp, kp, vtp, opart, lp, TOK/KS, KS);
        out_fused_kernel<<<dim3(64, 6), 256, 0, stream>>>(
            opart, lp, wout, bout, out, KS);
    } else {
        attn_kernel<<<dim3(TOK/128, 6, 1), 256, 0, stream>>>(
            qp, kp, vtp, op, (float*)d_ws, TOK, 1);
        out_kernel<<<dim3(64, 6), 256, 0, stream>>>(op, wout, bout, out);
    }
}

// Round 13
// 80.336 us; speedup vs baseline: 1.1126x; 1.1126x over previous
//
#include <hip/hip_runtime.h>
#include <hip/hip_bf16.h>

// Problem constants
#define TOK  4096      // tokens = 16*16*16
#define CH   384       // hidden
#define NH   6         // heads
#define HD   64        // head dim
#define NQKV 1152      // 3*CH

typedef __bf16 bf16x8 __attribute__((ext_vector_type(8)));
typedef float f32x4  __attribute__((ext_vector_type(4)));
typedef float f32x16 __attribute__((ext_vector_type(16)));
typedef unsigned short u16x8 __attribute__((ext_vector_type(8)));
typedef unsigned short u16x4 __attribute__((ext_vector_type(4)));
typedef unsigned int   u32x2 __attribute__((ext_vector_type(2)));
typedef unsigned int   u32x4 __attribute__((ext_vector_type(4)));

__device__ __forceinline__ unsigned short f2bf(float f) {
    unsigned int u = __builtin_bit_cast(unsigned int, f);
    u += 0x7FFFu + ((u >> 16) & 1u);   // round-to-nearest-even
    return (unsigned short)(u >> 16);
}

__device__ __forceinline__ float bf2f(unsigned short s) {
    return __builtin_bit_cast(float, (unsigned int)s << 16);
}

// pack two f32 -> one u32 of 2 bf16 (folds to v_cvt_pk_bf16_f32: 1 VALU op)
__device__ __forceinline__ unsigned int pk2(float a, float b) {
    __bf16 x = (__bf16)a, y = (__bf16)b;
    unsigned short ux = __builtin_bit_cast(unsigned short, x);
    unsigned short uy = __builtin_bit_cast(unsigned short, y);
    return (unsigned int)ux | ((unsigned int)uy << 16);
}

__device__ __forceinline__ f32x4 mfma_bf16(u16x8 a, u16x8 b, f32x4 c) {
    return __builtin_amdgcn_mfma_f32_16x16x32_bf16(
        __builtin_bit_cast(bf16x8, a), __builtin_bit_cast(bf16x8, b), c, 0, 0, 0);
}

__device__ __forceinline__ f32x16 mfma32(u16x8 a, u16x8 b, f32x16 c) {
    return __builtin_amdgcn_mfma_f32_32x32x16_bf16(
        __builtin_bit_cast(bf16x8, a), __builtin_bit_cast(bf16x8, b), c, 0, 0, 0);
}

// v_permlane32_swap_b32 (fallback: shfl)
__device__ __forceinline__ void plswap(unsigned int &x, unsigned int &y, int hi) {
#if __has_builtin(__builtin_amdgcn_permlane32_swap)
    u32x2 r = __builtin_amdgcn_permlane32_swap(x, y, false, false);
    x = r[0]; y = r[1];
#else
    unsigned int xs = (unsigned int)__shfl_xor((int)x, 32, 64);
    unsigned int ys = (unsigned int)__shfl_xor((int)y, 32, 64);
    unsigned int nx = hi ? ys : x;
    unsigned int ny = hi ? y  : xs;
    x = nx; y = ny;
#endif
}

__device__ __forceinline__ float partner32(float v, int hi) {
    unsigned int a = __builtin_bit_cast(unsigned int, v);
    unsigned int b = a;
    plswap(a, b, hi);
    return __builtin_bit_cast(float, hi ? a : b);
}

// ---------------------------------------------------------------------------
// Kernel 1: qkv = xt @ W_qkv.   A = xt[t][c] (x stored [c][t]), B = W_qkv[c][n]
// Q is scaled by 0.125*log2(e) (softmax scale + exp2-domain fold).
// Writes: Q [h][t][64], K [h][t][64], V^T [h][64][t]  (bf16)
// R5's 64x64 form (grid 64x18 = 1152 blocks): ledger-best "others" time.
// ---------------------------------------------------------------------------
__global__ __launch_bounds__(256) void qkv_kernel(
    const float* __restrict__ x, const float* __restrict__ w,
    unsigned short* __restrict__ qws, unsigned short* __restrict__ kws,
    unsigned short* __restrict__ vtws)
{
    __shared__ __align__(16) unsigned short As[64][32];   // [m][k]
    __shared__ __align__(16) unsigned short Bs[64][32];   // [n][k]
    const int tid = threadIdx.x;
    const int t0 = blockIdx.x * 64;
    const int by = blockIdx.y;            // 0..17
    const int n0 = by * 64;
    const int lane = tid & 63;
    const int wid  = tid >> 6;
    const int wr = wid >> 1, wc = wid & 1;
    const int l15 = lane & 15, lg = lane >> 4;
    const int sm  = tid & 63;
    const int skg = tid >> 6;

    f32x4 acc[2][2] = {};

    for (int k0 = 0; k0 < CH; k0 += 32) {
        float a[8], b[8];
        #pragma unroll
        for (int j = 0; j < 8; ++j) {
            a[j] = x[(k0 + skg*8 + j) * TOK + t0 + sm];
            b[j] = w[(k0 + skg*8 + j) * NQKV + n0 + sm];
        }
        u32x4 aw = { pk2(a[0],a[1]), pk2(a[2],a[3]), pk2(a[4],a[5]), pk2(a[6],a[7]) };
        u32x4 bw = { pk2(b[0],b[1]), pk2(b[2],b[3]), pk2(b[4],b[5]), pk2(b[6],b[7]) };
        __syncthreads();
        *reinterpret_cast<u32x4*>(&As[sm][skg*8]) = aw;
        *reinterpret_cast<u32x4*>(&Bs[sm][skg*8]) = bw;
        __syncthreads();

        u16x8 afr[2], bfr[2];
        #pragma unroll
        for (int mi = 0; mi < 2; ++mi)
            afr[mi] = *reinterpret_cast<const u16x8*>(&As[wr*32 + mi*16 + l15][lg*8]);
        #pragma unroll
        for (int ni = 0; ni < 2; ++ni)
            bfr[ni] = *reinterpret_cast<const u16x8*>(&Bs[wc*32 + ni*16 + l15][lg*8]);
        #pragma unroll
        for (int mi = 0; mi < 2; ++mi)
            #pragma unroll
            for (int ni = 0; ni < 2; ++ni)
                acc[mi][ni] = mfma_bf16(afr[mi], bfr[ni], acc[mi][ni]);
    }

    // qscale = 0.125 * log2(e): logits come out in exp2 domain
    const float qscale = (by < 6) ? 0.18033688011112042f : 1.0f;
    const int head = by % 6;
    #pragma unroll
    for (int mi = 0; mi < 2; ++mi)
    #pragma unroll
    for (int ni = 0; ni < 2; ++ni)
    #pragma unroll
    for (int r = 0; r < 4; ++r) {
        int t   = t0 + wr*32 + mi*16 + lg*4 + r;
        int dim = wc*32 + ni*16 + l15;
        unsigned short v = f2bf(acc[mi][ni][r] * qscale);
        if (by < 6)        qws[head*(TOK*HD) + t*HD + dim] = v;
        else if (by < 12)  kws[head*(TOK*HD) + t*HD + dim] = v;
        else               vtws[head*(TOK*HD) + dim*TOK + t] = v;
    }
}

// ---------------------------------------------------------------------------
// Kernel 2: flash attention — R11 EXACT (verified 41.7-42.2 µs x3, VGPR 76).
// 32x32 swapped-QK^T, in-register softmax, no max tracking (exp2-domain
// logits, |s| << 127). KBLK=128 staged per barrier pair; two sequential
// 64-key halves with st[2] reused. Register prefetch of next tile. lsum
// partner-merge deferred to epilogue. KS=8 (3/CU KS=4 tail regressed, R12).
// ---------------------------------------------------------------------------
__global__ __launch_bounds__(256, 3) void attn_kernel(
    const unsigned short* __restrict__ qws, const unsigned short* __restrict__ kws,
    const unsigned short* __restrict__ vtws, unsigned short* __restrict__ odst,
    float* __restrict__ lpart, int clen, int nchunks)
{
    __shared__ __align__(16) unsigned short Ks[128][64];    // [key][d], swizzled ^(row&7)
    __shared__ __align__(16) unsigned short Vts[64][128];   // [d][key], swizzled ^(row&15)
    const int tid = threadIdx.x;
    const int h  = blockIdx.y;
    const int chunk = blockIdx.z;
    const int kbeg = chunk * clen, kend = kbeg + clen;
    const int lane = tid & 63, wid = tid >> 6;
    const int l31 = lane & 31, hi = lane >> 5;
    const int krow = tid >> 3, kch = tid & 7;     // K staging: +i*32 rows
    const int vrow = tid >> 4, vch = tid & 15;    // V staging: +i*16 rows
    const int qrow = blockIdx.x * 128 + wid * 32 + l31;    // this lane's q row

    const unsigned short* qh = qws  + h*(TOK*HD);
    const unsigned short* kh = kws  + h*(TOK*HD);
    const unsigned short* vh = vtws + h*(TOK*HD);

    // Q B-frags (col=lane&31=q, k=d = c*16 + hi*8 + j)
    u16x8 qf[4];
    #pragma unroll
    for (int c = 0; c < 4; ++c)
        qf[c] = *reinterpret_cast<const u16x8*>(&qh[(size_t)qrow*HD + c*16 + hi*8]);

    f32x16 oaccT[2] = {};        // O^T: col=q(l31), row=d_local
    float lsum = 0.f;            // lane-local partial; partner-merged at end

    // prologue prefetch of tile 0 (4 K-frags + 4 V-frags per thread)
    u16x8 kreg[4], vreg[4];
    #pragma unroll
    for (int i = 0; i < 4; ++i) {
        kreg[i] = *reinterpret_cast<const u16x8*>(
            &kh[(size_t)(kbeg + krow + i*32)*HD + kch*8]);
        vreg[i] = *reinterpret_cast<const u16x8*>(
            &vh[(size_t)(vrow + i*16)*TOK + kbeg + vch*8]);
    }

    for (int kt = kbeg; kt < kend; kt += 128) {
        __syncthreads();   // prev tile's LDS reads done
        #pragma unroll
        for (int i = 0; i < 4; ++i) {
            int kr = krow + i*32;
            int vr = vrow + i*16;
            *reinterpret_cast<u16x8*>(&Ks[kr][(kch ^ (kr & 7))*8])   = kreg[i];
            *reinterpret_cast<u16x8*>(&Vts[vr][(vch ^ (vr & 15))*8]) = vreg[i];
        }
        const int ktn = (kt + 128 < kend) ? (kt + 128) : kt;
        #pragma unroll
        for (int i = 0; i < 4; ++i) {
            kreg[i] = *reinterpret_cast<const u16x8*>(
                &kh[(size_t)(ktn + krow + i*32)*HD + kch*8]);
            vreg[i] = *reinterpret_cast<const u16x8*>(
                &vh[(size_t)(vrow + i*16)*TOK + ktn + vch*8]);
        }
        __syncthreads();   // staging visible

        // two sequential 64-key halves (verified 64-key pipeline per half)
        #pragma unroll
        for (int H = 0; H < 2; ++H) {
            // S^T[key][q]: A=K rows (key = H*64 + g*32 + l31), B=Q
            f32x16 st[2] = {};
            #pragma unroll
            for (int g = 0; g < 2; ++g) {
                int r = H*64 + g*32 + l31;
                #pragma unroll
                for (int c = 0; c < 4; ++c) {
                    int chs = (c*2 + hi) ^ (r & 7);
                    u16x8 kf = *reinterpret_cast<const u16x8*>(&Ks[r][chs*8]);
                    st[g] = mfma32(kf, qf[c], st[g]);
                }
            }

            // p = exp2(s) directly (no max tracking)
            #pragma unroll
            for (int g = 0; g < 2; ++g)
                #pragma unroll
                for (int e = 0; e < 16; ++e)
                    st[g][e] = __builtin_amdgcn_exp2f(st[g][e]);

            // row sum: log-depth tree (lane-local; partner merge deferred)
            float tr[16];
            #pragma unroll
            for (int e = 0; e < 16; ++e)
                tr[e] = st[0][e] + st[1][e];
            #pragma unroll
            for (int w = 8; w >= 1; w >>= 1)
                #pragma unroll
                for (int e = 0; e < w; ++e)
                    tr[e] += tr[e+w];
            lsum += tr[0];

            // pack P to bf16 words: key(g, reg=4s+m) = H*64 + g*32 + 8s + m + 4*hi
            unsigned int wAw[2][4], wBw[2][4];
            #pragma unroll
            for (int g = 0; g < 2; ++g)
                #pragma unroll
                for (int s = 0; s < 4; ++s) {
                    wAw[g][s] = pk2(st[g][4*s+0], st[g][4*s+1]);
                    wBw[g][s] = pk2(st[g][4*s+2], st[g][4*s+3]);
                }

            // O^T += V^T P^T over this half's 64 key-columns
            #pragma unroll
            for (int ks = 0; ks < 4; ++ks) {
                int g = ks >> 1, u = (ks & 1) * 2;
                unsigned int a0 = wAw[g][u], a1 = wAw[g][u+1];
                unsigned int b0 = wBw[g][u], b1 = wBw[g][u+1];
                plswap(a0, a1, hi);
                plswap(b0, b1, hi);
                u32x4 af = { a0, b0, a1, b1 };
                u16x8 pfr = __builtin_bit_cast(u16x8, af);
                int cc = H*8 + ks*2 + hi;          // V col-chunk (16 per row)
                #pragma unroll
                for (int dh = 0; dh < 2; ++dh) {
                    int r = dh*32 + l31;
                    int ccs = cc ^ (r & 15);
                    u16x8 vf = *reinterpret_cast<const u16x8*>(&Vts[r][ccs*8]);
                    oaccT[dh] = mfma32(vf, pfr, oaccT[dh]);
                }
            }
        }
    }

    // merge lane partials (lane and lane^32 hold complementary key halves)
    lsum += partner32(lsum, hi);

    // epilogue: O^T element (dh, reg=4s+m) -> d = dh*32 + 8s + 4*hi + m, q = qrow
    if (nchunks == 1) {
        float inv = 1.0f / lsum;
        #pragma unroll
        for (int dh = 0; dh < 2; ++dh)
            #pragma unroll
            for (int s = 0; s < 4; ++s) {
                u16x4 v;
                #pragma unroll
                for (int m = 0; m < 4; ++m)
                    v[m] = f2bf(oaccT[dh][4*s+m] * inv);
                *reinterpret_cast<u16x4*>(
                    &odst[(size_t)qrow*CH + h*HD + dh*32 + s*8 + hi*4]) = v;
            }
    } else {
        const size_t cb = (size_t)(chunk*NH + h)*TOK;
        #pragma unroll
        for (int dh = 0; dh < 2; ++dh)
            #pragma unroll
            for (int s = 0; s < 4; ++s) {
                u16x4 v;
                #pragma unroll
                for (int m = 0; m < 4; ++m)
                    v[m] = f2bf(oaccT[dh][4*s+m]);
                *reinterpret_cast<u16x4*>(
                    &odst[(cb + qrow)*HD + dh*32 + s*8 + hi*4]) = v;
            }
        if (hi == 0)
            lpart[cb + qrow] = lsum;
    }
}

// ---------------------------------------------------------------------------
// Kernel 2b: combine k-chunks (standalone, fully parallel — R12's fusion
// into out's barrier-locked staging path regressed; reverted).
// out = (sum_c O_c) / (sum_c l_c). One thread per (h, t, 8-wide d group).
// ---------------------------------------------------------------------------
__global__ __launch_bounds__(256) void combine_kernel(
    const unsigned short* __restrict__ opart, const float* __restrict__ lpart,
    unsigned short* __restrict__ ob, int nchunks)
{
    const int gid = blockIdx.x * 256 + threadIdx.x;  // (h, t, dg)
    const int dg = gid & 7;
    const int t  = (gid >> 3) & (TOK - 1);
    const int h  = gid >> 15;
    const int row = h*TOK + t;

    float wsum = 0.f;
    float o[8] = {};
    for (int c = 0; c < nchunks; ++c) {
        wsum += lpart[c*(NH*TOK) + row];
        u16x8 ov = *reinterpret_cast<const u16x8*>(
            &opart[((size_t)(c*NH + h)*TOK + t)*HD + dg*8]);
        #pragma unroll
        for (int j = 0; j < 8; ++j)
            o[j] += bf2f(ov[j]);
    }
    const float inv = 1.0f / wsum;
    u16x8 res;
    #pragma unroll
    for (int j = 0; j < 8; ++j)
        res[j] = f2bf(o[j] * inv);
    *reinterpret_cast<u16x8*>(&ob[(size_t)t*CH + h*HD + dg*8]) = res;
}

// ---------------------------------------------------------------------------
// Kernel 3: out = O @ W_out + b_out, fp32 result in [t][CH] flat order.
// R5 structure (single buffer, 2 barriers).
// ---------------------------------------------------------------------------
__global__ __launch_bounds__(256) void out_kernel(
    const unsigned short* __restrict__ ob, const float* __restrict__ w,
    const float* __restrict__ bias, float* __restrict__ out)
{
    __shared__ __align__(16) unsigned short As[64][32];
    __shared__ __align__(16) unsigned short Bs[64][32];
    const int tid = threadIdx.x;
    const int t0 = blockIdx.x * 64;
    const int n0 = blockIdx.y * 64;
    const int lane = tid & 63, wid = tid >> 6;
    const int wr = wid >> 1, wc = wid & 1;
    const int l15 = lane & 15, lg = lane >> 4;
    const int sm = tid & 63, skg = tid >> 6;

    f32x4 acc[2][2] = {};

    for (int k0 = 0; k0 < CH; k0 += 32) {
        u16x8 av = *reinterpret_cast<const u16x8*>(&ob[(size_t)(t0+sm)*CH + k0 + skg*8]);
        float b[8];
        #pragma unroll
        for (int j = 0; j < 8; ++j)
            b[j] = w[(k0 + skg*8 + j) * CH + n0 + sm];
        u32x4 bw = { pk2(b[0],b[1]), pk2(b[2],b[3]), pk2(b[4],b[5]), pk2(b[6],b[7]) };
        __syncthreads();
        *reinterpret_cast<u16x8*>(&As[sm][skg*8]) = av;
        *reinterpret_cast<u32x4*>(&Bs[sm][skg*8]) = bw;
        __syncthreads();

        u16x8 afr[2], bfr[2];
        #pragma unroll
        for (int mi = 0; mi < 2; ++mi)
            afr[mi] = *reinterpret_cast<const u16x8*>(&As[wr*32 + mi*16 + l15][lg*8]);
        #pragma unroll
        for (int ni = 0; ni < 2; ++ni)
            bfr[ni] = *reinterpret_cast<const u16x8*>(&Bs[wc*32 + ni*16 + l15][lg*8]);
        #pragma unroll
        for (int mi = 0; mi < 2; ++mi)
            #pragma unroll
            for (int ni = 0; ni < 2; ++ni)
                acc[mi][ni] = mfma_bf16(afr[mi], bfr[ni], acc[mi][ni]);
    }

    #pragma unroll
    for (int mi = 0; mi < 2; ++mi)
    #pragma unroll
    for (int ni = 0; ni < 2; ++ni)
    #pragma unroll
    for (int r = 0; r < 4; ++r) {
        int t = t0 + wr*32 + mi*16 + lg*4 + r;
        int n = n0 + wc*32 + ni*16 + l15;
        out[t*CH + n] = acc[mi][ni][r] + bias[n];
    }
}

// ---------------------------------------------------------------------------
extern "C" void kernel_launch(void* const* d_in, const int* in_sizes, int n_in,
                              void* d_out, int out_size, void* d_ws, size_t ws_size,
                              hipStream_t stream) {
    const float* x    = (const float*)d_in[0];   // [384][4096] (c-major)
    const float* wqkv = (const float*)d_in[1];   // [384][1152]
    const float* wout = (const float*)d_in[2];   // [384][384]
    const float* bout = (const float*)d_in[3];   // [384]
    float* out = (float*)d_out;                  // [4096][384] flat

    unsigned short* ws  = (unsigned short*)d_ws;
    unsigned short* qp  = ws;
    unsigned short* kp  = qp + NH*TOK*HD;
    unsigned short* vtp = kp + NH*TOK*HD;
    unsigned short* op  = vtp + NH*TOK*HD;

    const size_t baseB = (size_t)(3*NH*TOK*HD + TOK*CH) * 2;
    const size_t perC  = (size_t)NH*TOK*HD*2 + (size_t)NH*TOK*4;   // opart + lpart
    int KS = 1;
    if      (baseB + 8*perC <= ws_size) KS = 8;
    else if (baseB + 4*perC <= ws_size) KS = 4;
    else if (baseB + 2*perC <= ws_size) KS = 2;

    qkv_kernel<<<dim3(64, 18), 256, 0, stream>>>(x, wqkv, qp, kp, vtp);

    if (KS > 1) {
        unsigned short* opart = op + (size_t)TOK*CH;
        float* lp = (float*)(opart + (size_t)KS*NH*TOK*HD);
        attn_kernel<<<dim3(TOK/128, 6, KS), 256, 0, stream>>>(
            qp, kp, vtp, opart, lp, TOK/KS, KS);
        combine_kernel<<<dim3(NH*TOK*HD/8/256), 256, 0, stream>>>(
            opart, lp, op, KS);
    } else {
        attn_kernel<<<dim3(TOK/128, 6, 1), 256, 0, stream>>>(
            qp, kp, vtp, op, (float*)d_ws, TOK, 1);
    }

    out_kernel<<<dim3(64, 6), 256, 0, stream>>>(op, wout, bout, out);
}

// Round 14
// 79.771 us; speedup vs baseline: 1.1205x; 1.0071x over previous
//
#include <hip/hip_runtime.h>
#include <hip/hip_bf16.h>

// Problem constants
#define TOK  4096      // tokens = 16*16*16
#define CH   384       // hidden
#define NH   6         // heads
#define HD   64        // head dim
#define NQKV 1152      // 3*CH

// GEMM LDS tiles: row stride padded 32 -> 40 u16 (80 B = 20 banks).
// Unpadded 64 B stride = 16 banks made the 16-row MFMA fragment read an
// 8-way bank conflict and the 64-row staging write ~32-way (G4 trap).
// 80 B spreads 16 rows over 8 bank-groups -> 2-way (free, m136).
#define LDP 40

typedef __bf16 bf16x8 __attribute__((ext_vector_type(8)));
typedef float f32x4  __attribute__((ext_vector_type(4)));
typedef float f32x16 __attribute__((ext_vector_type(16)));
typedef unsigned short u16x8 __attribute__((ext_vector_type(8)));
typedef unsigned short u16x4 __attribute__((ext_vector_type(4)));
typedef unsigned int   u32x2 __attribute__((ext_vector_type(2)));
typedef unsigned int   u32x4 __attribute__((ext_vector_type(4)));

__device__ __forceinline__ unsigned short f2bf(float f) {
    unsigned int u = __builtin_bit_cast(unsigned int, f);
    u += 0x7FFFu + ((u >> 16) & 1u);   // round-to-nearest-even
    return (unsigned short)(u >> 16);
}

__device__ __forceinline__ float bf2f(unsigned short s) {
    return __builtin_bit_cast(float, (unsigned int)s << 16);
}

// pack two f32 -> one u32 of 2 bf16 (folds to v_cvt_pk_bf16_f32: 1 VALU op)
__device__ __forceinline__ unsigned int pk2(float a, float b) {
    __bf16 x = (__bf16)a, y = (__bf16)b;
    unsigned short ux = __builtin_bit_cast(unsigned short, x);
    unsigned short uy = __builtin_bit_cast(unsigned short, y);
    return (unsigned int)ux | ((unsigned int)uy << 16);
}

__device__ __forceinline__ f32x4 mfma_bf16(u16x8 a, u16x8 b, f32x4 c) {
    return __builtin_amdgcn_mfma_f32_16x16x32_bf16(
        __builtin_bit_cast(bf16x8, a), __builtin_bit_cast(bf16x8, b), c, 0, 0, 0);
}

__device__ __forceinline__ f32x16 mfma32(u16x8 a, u16x8 b, f32x16 c) {
    return __builtin_amdgcn_mfma_f32_32x32x16_bf16(
        __builtin_bit_cast(bf16x8, a), __builtin_bit_cast(bf16x8, b), c, 0, 0, 0);
}

// v_permlane32_swap_b32 (fallback: shfl)
__device__ __forceinline__ void plswap(unsigned int &x, unsigned int &y, int hi) {
#if __has_builtin(__builtin_amdgcn_permlane32_swap)
    u32x2 r = __builtin_amdgcn_permlane32_swap(x, y, false, false);
    x = r[0]; y = r[1];
#else
    unsigned int xs = (unsigned int)__shfl_xor((int)x, 32, 64);
    unsigned int ys = (unsigned int)__shfl_xor((int)y, 32, 64);
    unsigned int nx = hi ? ys : x;
    unsigned int ny = hi ? y  : xs;
    x = nx; y = ny;
#endif
}

__device__ __forceinline__ float partner32(float v, int hi) {
    unsigned int a = __builtin_bit_cast(unsigned int, v);
    unsigned int b = a;
    plswap(a, b, hi);
    return __builtin_bit_cast(float, hi ? a : b);
}

// ---------------------------------------------------------------------------
// Kernel 1: qkv = xt @ W_qkv.   A = xt[t][c] (x stored [c][t]), B = W_qkv[c][n]
// Q is scaled by 0.125*log2(e) (softmax scale + exp2-domain fold).
// Writes: Q [h][t][64], K [h][t][64], V^T [h][64][t]  (bf16)
// R5's 64x64 form (grid 64x18 = 1152 blocks) + padded LDS stride (R14).
// ---------------------------------------------------------------------------
__global__ __launch_bounds__(256) void qkv_kernel(
    const float* __restrict__ x, const float* __restrict__ w,
    unsigned short* __restrict__ qws, unsigned short* __restrict__ kws,
    unsigned short* __restrict__ vtws)
{
    __shared__ __align__(16) unsigned short As[64][LDP];   // [m][k], padded
    __shared__ __align__(16) unsigned short Bs[64][LDP];   // [n][k], padded
    const int tid = threadIdx.x;
    const int t0 = blockIdx.x * 64;
    const int by = blockIdx.y;            // 0..17
    const int n0 = by * 64;
    const int lane = tid & 63;
    const int wid  = tid >> 6;
    const int wr = wid >> 1, wc = wid & 1;
    const int l15 = lane & 15, lg = lane >> 4;
    const int sm  = tid & 63;
    const int skg = tid >> 6;

    f32x4 acc[2][2] = {};

    for (int k0 = 0; k0 < CH; k0 += 32) {
        float a[8], b[8];
        #pragma unroll
        for (int j = 0; j < 8; ++j) {
            a[j] = x[(k0 + skg*8 + j) * TOK + t0 + sm];
            b[j] = w[(k0 + skg*8 + j) * NQKV + n0 + sm];
        }
        u32x4 aw = { pk2(a[0],a[1]), pk2(a[2],a[3]), pk2(a[4],a[5]), pk2(a[6],a[7]) };
        u32x4 bw = { pk2(b[0],b[1]), pk2(b[2],b[3]), pk2(b[4],b[5]), pk2(b[6],b[7]) };
        __syncthreads();
        *reinterpret_cast<u32x4*>(&As[sm][skg*8]) = aw;
        *reinterpret_cast<u32x4*>(&Bs[sm][skg*8]) = bw;
        __syncthreads();

        u16x8 afr[2], bfr[2];
        #pragma unroll
        for (int mi = 0; mi < 2; ++mi)
            afr[mi] = *reinterpret_cast<const u16x8*>(&As[wr*32 + mi*16 + l15][lg*8]);
        #pragma unroll
        for (int ni = 0; ni < 2; ++ni)
            bfr[ni] = *reinterpret_cast<const u16x8*>(&Bs[wc*32 + ni*16 + l15][lg*8]);
        #pragma unroll
        for (int mi = 0; mi < 2; ++mi)
            #pragma unroll
            for (int ni = 0; ni < 2; ++ni)
                acc[mi][ni] = mfma_bf16(afr[mi], bfr[ni], acc[mi][ni]);
    }

    // qscale = 0.125 * log2(e): logits come out in exp2 domain
    const float qscale = (by < 6) ? 0.18033688011112042f : 1.0f;
    const int head = by % 6;
    #pragma unroll
    for (int mi = 0; mi < 2; ++mi)
    #pragma unroll
    for (int ni = 0; ni < 2; ++ni)
    #pragma unroll
    for (int r = 0; r < 4; ++r) {
        int t   = t0 + wr*32 + mi*16 + lg*4 + r;
        int dim = wc*32 + ni*16 + l15;
        unsigned short v = f2bf(acc[mi][ni][r] * qscale);
        if (by < 6)        qws[head*(TOK*HD) + t*HD + dim] = v;
        else if (by < 12)  kws[head*(TOK*HD) + t*HD + dim] = v;
        else               vtws[head*(TOK*HD) + dim*TOK + t] = v;
    }
}

// ---------------------------------------------------------------------------
// Kernel 2: flash attention — FROZEN (verified 41.7-42.2 µs x4, VGPR 76).
// 32x32 swapped-QK^T, in-register softmax, no max tracking (exp2-domain
// logits, |s| << 127). KBLK=128 staged per barrier pair; two sequential
// 64-key halves with st[2] reused. Register prefetch of next tile. lsum
// partner-merge deferred to epilogue. KS=8.
// ---------------------------------------------------------------------------
__global__ __launch_bounds__(256, 3) void attn_kernel(
    const unsigned short* __restrict__ qws, const unsigned short* __restrict__ kws,
    const unsigned short* __restrict__ vtws, unsigned short* __restrict__ odst,
    float* __restrict__ lpart, int clen, int nchunks)
{
    __shared__ __align__(16) unsigned short Ks[128][64];    // [key][d], swizzled ^(row&7)
    __shared__ __align__(16) unsigned short Vts[64][128];   // [d][key], swizzled ^(row&15)
    const int tid = threadIdx.x;
    const int h  = blockIdx.y;
    const int chunk = blockIdx.z;
    const int kbeg = chunk * clen, kend = kbeg + clen;
    const int lane = tid & 63, wid = tid >> 6;
    const int l31 = lane & 31, hi = lane >> 5;
    const int krow = tid >> 3, kch = tid & 7;     // K staging: +i*32 rows
    const int vrow = tid >> 4, vch = tid & 15;    // V staging: +i*16 rows
    const int qrow = blockIdx.x * 128 + wid * 32 + l31;    // this lane's q row

    const unsigned short* qh = qws  + h*(TOK*HD);
    const unsigned short* kh = kws  + h*(TOK*HD);
    const unsigned short* vh = vtws + h*(TOK*HD);

    // Q B-frags (col=lane&31=q, k=d = c*16 + hi*8 + j)
    u16x8 qf[4];
    #pragma unroll
    for (int c = 0; c < 4; ++c)
        qf[c] = *reinterpret_cast<const u16x8*>(&qh[(size_t)qrow*HD + c*16 + hi*8]);

    f32x16 oaccT[2] = {};        // O^T: col=q(l31), row=d_local
    float lsum = 0.f;            // lane-local partial; partner-merged at end

    // prologue prefetch of tile 0 (4 K-frags + 4 V-frags per thread)
    u16x8 kreg[4], vreg[4];
    #pragma unroll
    for (int i = 0; i < 4; ++i) {
        kreg[i] = *reinterpret_cast<const u16x8*>(
            &kh[(size_t)(kbeg + krow + i*32)*HD + kch*8]);
        vreg[i] = *reinterpret_cast<const u16x8*>(
            &vh[(size_t)(vrow + i*16)*TOK + kbeg + vch*8]);
    }

    for (int kt = kbeg; kt < kend; kt += 128) {
        __syncthreads();   // prev tile's LDS reads done
        #pragma unroll
        for (int i = 0; i < 4; ++i) {
            int kr = krow + i*32;
            int vr = vrow + i*16;
            *reinterpret_cast<u16x8*>(&Ks[kr][(kch ^ (kr & 7))*8])   = kreg[i];
            *reinterpret_cast<u16x8*>(&Vts[vr][(vch ^ (vr & 15))*8]) = vreg[i];
        }
        const int ktn = (kt + 128 < kend) ? (kt + 128) : kt;
        #pragma unroll
        for (int i = 0; i < 4; ++i) {
            kreg[i] = *reinterpret_cast<const u16x8*>(
                &kh[(size_t)(ktn + krow + i*32)*HD + kch*8]);
            vreg[i] = *reinterpret_cast<const u16x8*>(
                &vh[(size_t)(vrow + i*16)*TOK + ktn + vch*8]);
        }
        __syncthreads();   // staging visible

        // two sequential 64-key halves (verified 64-key pipeline per half)
        #pragma unroll
        for (int H = 0; H < 2; ++H) {
            // S^T[key][q]: A=K rows (key = H*64 + g*32 + l31), B=Q
            f32x16 st[2] = {};
            #pragma unroll
            for (int g = 0; g < 2; ++g) {
                int r = H*64 + g*32 + l31;
                #pragma unroll
                for (int c = 0; c < 4; ++c) {
                    int chs = (c*2 + hi) ^ (r & 7);
                    u16x8 kf = *reinterpret_cast<const u16x8*>(&Ks[r][chs*8]);
                    st[g] = mfma32(kf, qf[c], st[g]);
                }
            }

            // p = exp2(s) directly (no max tracking)
            #pragma unroll
            for (int g = 0; g < 2; ++g)
                #pragma unroll
                for (int e = 0; e < 16; ++e)
                    st[g][e] = __builtin_amdgcn_exp2f(st[g][e]);

            // row sum: log-depth tree (lane-local; partner merge deferred)
            float tr[16];
            #pragma unroll
            for (int e = 0; e < 16; ++e)
                tr[e] = st[0][e] + st[1][e];
            #pragma unroll
            for (int w = 8; w >= 1; w >>= 1)
                #pragma unroll
                for (int e = 0; e < w; ++e)
                    tr[e] += tr[e+w];
            lsum += tr[0];

            // pack P to bf16 words: key(g, reg=4s+m) = H*64 + g*32 + 8s + m + 4*hi
            unsigned int wAw[2][4], wBw[2][4];
            #pragma unroll
            for (int g = 0; g < 2; ++g)
                #pragma unroll
                for (int s = 0; s < 4; ++s) {
                    wAw[g][s] = pk2(st[g][4*s+0], st[g][4*s+1]);
                    wBw[g][s] = pk2(st[g][4*s+2], st[g][4*s+3]);
                }

            // O^T += V^T P^T over this half's 64 key-columns
            #pragma unroll
            for (int ks = 0; ks < 4; ++ks) {
                int g = ks >> 1, u = (ks & 1) * 2;
                unsigned int a0 = wAw[g][u], a1 = wAw[g][u+1];
                unsigned int b0 = wBw[g][u], b1 = wBw[g][u+1];
                plswap(a0, a1, hi);
                plswap(b0, b1, hi);
                u32x4 af = { a0, b0, a1, b1 };
                u16x8 pfr = __builtin_bit_cast(u16x8, af);
                int cc = H*8 + ks*2 + hi;          // V col-chunk (16 per row)
                #pragma unroll
                for (int dh = 0; dh < 2; ++dh) {
                    int r = dh*32 + l31;
                    int ccs = cc ^ (r & 15);
                    u16x8 vf = *reinterpret_cast<const u16x8*>(&Vts[r][ccs*8]);
                    oaccT[dh] = mfma32(vf, pfr, oaccT[dh]);
                }
            }
        }
    }

    // merge lane partials (lane and lane^32 hold complementary key halves)
    lsum += partner32(lsum, hi);

    // epilogue: O^T element (dh, reg=4s+m) -> d = dh*32 + 8s + 4*hi + m, q = qrow
    if (nchunks == 1) {
        float inv = 1.0f / lsum;
        #pragma unroll
        for (int dh = 0; dh < 2; ++dh)
            #pragma unroll
            for (int s = 0; s < 4; ++s) {
                u16x4 v;
                #pragma unroll
                for (int m = 0; m < 4; ++m)
                    v[m] = f2bf(oaccT[dh][4*s+m] * inv);
                *reinterpret_cast<u16x4*>(
                    &odst[(size_t)qrow*CH + h*HD + dh*32 + s*8 + hi*4]) = v;
            }
    } else {
        const size_t cb = (size_t)(chunk*NH + h)*TOK;
        #pragma unroll
        for (int dh = 0; dh < 2; ++dh)
            #pragma unroll
            for (int s = 0; s < 4; ++s) {
                u16x4 v;
                #pragma unroll
                for (int m = 0; m < 4; ++m)
                    v[m] = f2bf(oaccT[dh][4*s+m]);
                *reinterpret_cast<u16x4*>(
                    &odst[(cb + qrow)*HD + dh*32 + s*8 + hi*4]) = v;
            }
        if (hi == 0)
            lpart[cb + qrow] = lsum;
    }
}

// ---------------------------------------------------------------------------
// Kernel 2b: combine k-chunks (standalone, fully parallel).
// out = (sum_c O_c) / (sum_c l_c). One thread per (h, t, 8-wide d group).
// ---------------------------------------------------------------------------
__global__ __launch_bounds__(256) void combine_kernel(
    const unsigned short* __restrict__ opart, const float* __restrict__ lpart,
    unsigned short* __restrict__ ob, int nchunks)
{
    const int gid = blockIdx.x * 256 + threadIdx.x;  // (h, t, dg)
    const int dg = gid & 7;
    const int t  = (gid >> 3) & (TOK - 1);
    const int h  = gid >> 15;
    const int row = h*TOK + t;

    float wsum = 0.f;
    float o[8] = {};
    for (int c = 0; c < nchunks; ++c) {
        wsum += lpart[c*(NH*TOK) + row];
        u16x8 ov = *reinterpret_cast<const u16x8*>(
            &opart[((size_t)(c*NH + h)*TOK + t)*HD + dg*8]);
        #pragma unroll
        for (int j = 0; j < 8; ++j)
            o[j] += bf2f(ov[j]);
    }
    const float inv = 1.0f / wsum;
    u16x8 res;
    #pragma unroll
    for (int j = 0; j < 8; ++j)
        res[j] = f2bf(o[j] * inv);
    *reinterpret_cast<u16x8*>(&ob[(size_t)t*CH + h*HD + dg*8]) = res;
}

// ---------------------------------------------------------------------------
// Kernel 3: out = O @ W_out + b_out, fp32 result in [t][CH] flat order.
// R5 structure + padded LDS stride (R14).
// ---------------------------------------------------------------------------
__global__ __launch_bounds__(256) void out_kernel(
    const unsigned short* __restrict__ ob, const float* __restrict__ w,
    const float* __restrict__ bias, float* __restrict__ out)
{
    __shared__ __align__(16) unsigned short As[64][LDP];
    __shared__ __align__(16) unsigned short Bs[64][LDP];
    const int tid = threadIdx.x;
    const int t0 = blockIdx.x * 64;
    const int n0 = blockIdx.y * 64;
    const int lane = tid & 63, wid = tid >> 6;
    const int wr = wid >> 1, wc = wid & 1;
    const int l15 = lane & 15, lg = lane >> 4;
    const int sm = tid & 63, skg = tid >> 6;

    f32x4 acc[2][2] = {};

    for (int k0 = 0; k0 < CH; k0 += 32) {
        u16x8 av = *reinterpret_cast<const u16x8*>(&ob[(size_t)(t0+sm)*CH + k0 + skg*8]);
        float b[8];
        #pragma unroll
        for (int j = 0; j < 8; ++j)
            b[j] = w[(k0 + skg*8 + j) * CH + n0 + sm];
        u32x4 bw = { pk2(b[0],b[1]), pk2(b[2],b[3]), pk2(b[4],b[5]), pk2(b[6],b[7]) };
        __syncthreads();
        *reinterpret_cast<u16x8*>(&As[sm][skg*8]) = av;
        *reinterpret_cast<u32x4*>(&Bs[sm][skg*8]) = bw;
        __syncthreads();

        u16x8 afr[2], bfr[2];
        #pragma unroll
        for (int mi = 0; mi < 2; ++mi)
            afr[mi] = *reinterpret_cast<const u16x8*>(&As[wr*32 + mi*16 + l15][lg*8]);
        #pragma unroll
        for (int ni = 0; ni < 2; ++ni)
            bfr[ni] = *reinterpret_cast<const u16x8*>(&Bs[wc*32 + ni*16 + l15][lg*8]);
        #pragma unroll
        for (int mi = 0; mi < 2; ++mi)
            #pragma unroll
            for (int ni = 0; ni < 2; ++ni)
                acc[mi][ni] = mfma_bf16(afr[mi], bfr[ni], acc[mi][ni]);
    }

    #pragma unroll
    for (int mi = 0; mi < 2; ++mi)
    #pragma unroll
    for (int ni = 0; ni < 2; ++ni)
    #pragma unroll
    for (int r = 0; r < 4; ++r) {
        int t = t0 + wr*32 + mi*16 + lg*4 + r;
        int n = n0 + wc*32 + ni*16 + l15;
        out[t*CH + n] = acc[mi][ni][r] + bias[n];
    }
}

// ---------------------------------------------------------------------------
extern "C" void kernel_launch(void* const* d_in, const int* in_sizes, int n_in,
                              void* d_out, int out_size, void* d_ws, size_t ws_size,
                              hipStream_t stream) {
    const float* x    = (const float*)d_in[0];   // [384][4096] (c-major)
    const float* wqkv = (const float*)d_in[1];   // [384][1152]
    const float* wout = (const float*)d_in[2];   // [384][384]
    const float* bout = (const float*)d_in[3];   // [384]
    float* out = (float*)d_out;                  // [4096][384] flat

    unsigned short* ws  = (unsigned short*)d_ws;
    unsigned short* qp  = ws;
    unsigned short* kp  = qp + NH*TOK*HD;
    unsigned short* vtp = kp + NH*TOK*HD;
    unsigned short* op  = vtp + NH*TOK*HD;

    const size_t baseB = (size_t)(3*NH*TOK*HD + TOK*CH) * 2;
    const size_t perC  = (size_t)NH*TOK*HD*2 + (size_t)NH*TOK*4;   // opart + lpart
    int KS = 1;
    if      (baseB + 8*perC <= ws_size) KS = 8;
    else if (baseB + 4*perC <= ws_size) KS = 4;
    else if (baseB + 2*perC <= ws_size) KS = 2;

    qkv_kernel<<<dim3(64, 18), 256, 0, stream>>>(x, wqkv, qp, kp, vtp);

    if (KS > 1) {
        unsigned short* opart = op + (size_t)TOK*CH;
        float* lp = (float*)(opart + (size_t)KS*NH*TOK*HD);
        attn_kernel<<<dim3(TOK/128, 6, KS), 256, 0, stream>>>(
            qp, kp, vtp, opart, lp, TOK/KS, KS);
        combine_kernel<<<dim3(NH*TOK*HD/8/256), 256, 0, stream>>>(
            opart, lp, op, KS);
    } else {
        attn_kernel<<<dim3(TOK/128, 6, 1), 256, 0, stream>>>(
            qp, kp, vtp, op, (float*)d_ws, TOK, 1);
    }

    out_kernel<<<dim3(64, 6), 256, 0, stream>>>(op, wout, bout, out);
}